// Round 5
// baseline (25.420 us; speedup 1.0000x reference)
//
#include <hip/hip_runtime.h>
#include <hip/hip_bf16.h>

#define N_NODES 100000
#define D 128
#define N_EDGES 1000000
#define K1_BLOCKS 2048   // 8192 waves = full occupancy, persistent grid-stride

// Kernel 1: per-node scores, persistent waves with prefetch pipeline.
// 16 lanes per node, 4 nodes/wave-iteration, ~3 iterations/wave.
// s[0 .. N_NODES)         = z[n] . W[0:128] + b   (src score, bias folded)
// s[N_NODES .. 2N_NODES)  = z[n] . W[128:256]     (dst score)
__global__ void __launch_bounds__(256) node_scores_kernel(
    const float* __restrict__ z, const float* __restrict__ W,
    const float* __restrict__ b, float* __restrict__ s) {
  const int lane = threadIdx.x & 63;
  const int sub  = lane >> 4;        // node within group (0..3)
  const int l16  = lane & 15;        // lane within 16-lane group
  const int wave0 = (blockIdx.x * blockDim.x + threadIdx.x) >> 6;  // 0..8191
  const int wstride = K1_BLOCKS * 256 / 64;  // 8192

  // loop-invariant: W fragments in registers, bias
  const float4* Wv = reinterpret_cast<const float4*>(W);
  const float4 ws0 = Wv[l16],      ws1 = Wv[16 + l16];
  const float4 wd0 = Wv[32 + l16], wd1 = Wv[48 + l16];
  const float bias = b[0];

  const int ngroups = N_NODES / 4;   // 25000

  int g = wave0;
  if (g >= ngroups) return;

  // prime the pipeline: loads for group g in flight
  const float4* zrow = reinterpret_cast<const float4*>(z + (size_t)(g * 4 + sub) * D);
  float4 z0 = zrow[l16];
  float4 z1 = zrow[16 + l16];

  while (true) {
    const int gn = g + wstride;
    float4 n0, n1;
    const bool more = gn < ngroups;
    if (more) {
      // issue next group's loads BEFORE consuming current ones
      const float4* zn = reinterpret_cast<const float4*>(z + (size_t)(gn * 4 + sub) * D);
      n0 = zn[l16];
      n1 = zn[16 + l16];
    }

    float a = z0.x * ws0.x + z0.y * ws0.y + z0.z * ws0.z + z0.w * ws0.w
            + z1.x * ws1.x + z1.y * ws1.y + z1.z * ws1.z + z1.w * ws1.w;
    float c = z0.x * wd0.x + z0.y * wd0.y + z0.z * wd0.z + z0.w * wd0.w
            + z1.x * wd1.x + z1.y * wd1.y + z1.z * wd1.z + z1.w * wd1.w;

    #pragma unroll
    for (int off = 8; off >= 1; off >>= 1) {
      a += __shfl_xor(a, off, 64);
      c += __shfl_xor(c, off, 64);
    }
    if (l16 == 0) {
      const int node = g * 4 + sub;
      s[node] = a + bias;
      s[N_NODES + node] = c;
    }

    if (!more) break;
    z0 = n0; z1 = n1; g = gn;
  }
}

// Kernel 2: 2 edges per thread (~7812 one-shot waves), L2-resident gathers.
__global__ void __launch_bounds__(256) edge_kernel(
    const int* __restrict__ idx, const float* __restrict__ s,
    float* __restrict__ out) {
  int t = blockIdx.x * blockDim.x + threadIdx.x;
  if (t * 2 >= N_EDGES) return;
  const int2 sv = reinterpret_cast<const int2*>(idx)[t];            // src row
  const int2 dv = reinterpret_cast<const int2*>(idx + N_EDGES)[t];  // dst row
  const float* __restrict__ sd = s + N_NODES;

  float l0 = s[sv.x] + sd[dv.x];
  float l1 = s[sv.y] + sd[dv.y];

  float2 o;
  o.x = 1.0f / (1.0f + __expf(-l0));
  o.y = 1.0f / (1.0f + __expf(-l1));
  reinterpret_cast<float2*>(out)[t] = o;
}

extern "C" void kernel_launch(void* const* d_in, const int* in_sizes, int n_in,
                              void* d_out, int out_size, void* d_ws, size_t ws_size,
                              hipStream_t stream) {
  const float* z   = (const float*)d_in[0];
  const int*   idx = (const int*)d_in[1];
  const float* W   = (const float*)d_in[2];
  const float* b   = (const float*)d_in[3];
  float* out = (float*)d_out;
  float* s   = (float*)d_ws;   // 2 * N_NODES floats = 800 KB

  node_scores_kernel<<<K1_BLOCKS, 256, 0, stream>>>(z, W, b, s);

  int blocks2 = (N_EDGES / 2 + 255) / 256;  // 1954
  edge_kernel<<<blocks2, 256, 0, stream>>>(idx, s, out);
}

// Round 6
// 24.994 us; speedup vs baseline: 1.0170x; 1.0170x over previous
//
#include <hip/hip_runtime.h>
#include <hip/hip_bf16.h>

#define N_NODES 100000
#define D 128
#define N_EDGES 1000000

typedef float v2f __attribute__((ext_vector_type(2)));
typedef int   v2i __attribute__((ext_vector_type(2)));

// Kernel 1: per-node scores. 8 lanes per node, 8 nodes/wave, one-shot grid.
// Score table interleaved: s2[n] = { z[n].W_src + b , z[n].W_dst }
__global__ void __launch_bounds__(256, 4) node_scores_kernel(
    const float* __restrict__ z, const float* __restrict__ W,
    const float* __restrict__ b, v2f* __restrict__ s2) {
  const int tid  = blockIdx.x * blockDim.x + threadIdx.x;
  const int wave = tid >> 6;         // 0..12499 (exact)
  const int lane = threadIdx.x & 63;
  const int sub  = lane >> 3;        // node within wave (0..7)
  const int l8   = lane & 7;         // lane within 8-lane group
  const int node = wave * 8 + sub;   // N_NODES % 8 == 0 -> no guard

  // lane covers float4 chunks l8, 8+l8, 16+l8, 24+l8 of the 32-chunk row
  const float4* zrow = reinterpret_cast<const float4*>(z + (size_t)node * D);
  const float4 z0 = zrow[l8];
  const float4 z1 = zrow[8 + l8];
  const float4 z2 = zrow[16 + l8];
  const float4 z3 = zrow[24 + l8];

  const float4* Wv = reinterpret_cast<const float4*>(W);
  const float4 ws0 = Wv[l8],      ws1 = Wv[8 + l8];
  const float4 ws2 = Wv[16 + l8], ws3 = Wv[24 + l8];
  const float4 wd0 = Wv[32 + l8], wd1 = Wv[40 + l8];
  const float4 wd2 = Wv[48 + l8], wd3 = Wv[56 + l8];

  float a = z0.x * ws0.x + z0.y * ws0.y + z0.z * ws0.z + z0.w * ws0.w
          + z1.x * ws1.x + z1.y * ws1.y + z1.z * ws1.z + z1.w * ws1.w
          + z2.x * ws2.x + z2.y * ws2.y + z2.z * ws2.z + z2.w * ws2.w
          + z3.x * ws3.x + z3.y * ws3.y + z3.z * ws3.z + z3.w * ws3.w;
  float c = z0.x * wd0.x + z0.y * wd0.y + z0.z * wd0.z + z0.w * wd0.w
          + z1.x * wd1.x + z1.y * wd1.y + z1.z * wd1.z + z1.w * wd1.w
          + z2.x * wd2.x + z2.y * wd2.y + z2.z * wd2.z + z2.w * wd2.w
          + z3.x * wd3.x + z3.y * wd3.y + z3.z * wd3.z + z3.w * wd3.w;

  // 3-level butterfly within each 8-lane group
  #pragma unroll
  for (int off = 4; off >= 1; off >>= 1) {
    a += __shfl_xor(a, off, 64);
    c += __shfl_xor(c, off, 64);
  }
  if (l8 == 0) {
    v2f st;
    st.x = a + b[0];
    st.y = c;
    s2[node] = st;      // single 8B store per node
  }
}

// Kernel 2: 2 edges/thread; random 4B gathers into the 800KB pair table.
// idx / out are stream-once -> non-temporal.
__global__ void __launch_bounds__(256) edge_kernel(
    const int* __restrict__ idx, const float* __restrict__ sp,
    float* __restrict__ out) {
  int t = blockIdx.x * blockDim.x + threadIdx.x;
  if (t * 2 >= N_EDGES) return;
  const v2i sv = __builtin_nontemporal_load(
      reinterpret_cast<const v2i*>(idx) + t);            // src row
  const v2i dv = __builtin_nontemporal_load(
      reinterpret_cast<const v2i*>(idx + N_EDGES) + t);  // dst row

  // pair layout: sp[2*n] = src score (+bias), sp[2*n+1] = dst score
  float l0 = sp[2 * sv.x] + sp[2 * dv.x + 1];
  float l1 = sp[2 * sv.y] + sp[2 * dv.y + 1];

  v2f o;
  o.x = 1.0f / (1.0f + __expf(-l0));
  o.y = 1.0f / (1.0f + __expf(-l1));
  __builtin_nontemporal_store(o, reinterpret_cast<v2f*>(out) + t);
}

extern "C" void kernel_launch(void* const* d_in, const int* in_sizes, int n_in,
                              void* d_out, int out_size, void* d_ws, size_t ws_size,
                              hipStream_t stream) {
  const float* z   = (const float*)d_in[0];
  const int*   idx = (const int*)d_in[1];
  const float* W   = (const float*)d_in[2];
  const float* b   = (const float*)d_in[3];
  float* out = (float*)d_out;
  v2f*   s2  = (v2f*)d_ws;   // N_NODES float2 pairs = 800 KB

  // Kernel 1: 8 nodes/wave, 4 waves/block -> 32 nodes/block, exact grid
  node_scores_kernel<<<N_NODES / 32, 256, 0, stream>>>(z, W, b, s2);

  // Kernel 2: 2 edges per thread
  int blocks2 = (N_EDGES / 2 + 255) / 256;  // 1954
  edge_kernel<<<blocks2, 256, 0, stream>>>(idx, (const float*)s2, out);
}